// Round 7
// baseline (853.479 us; speedup 1.0000x reference)
//
#include <hip/hip_runtime.h>
#include <hip/hip_bf16.h>

#define NTOK 32768
#define KEMB 4096
#define DDIM 256
#define DECAYF 0.99f
#define EPSF 1e-5f
#define KSPLIT 256          // hi-only fp16: Xh . Ch, error handled by flag+refine
#define FLAG_THETA 0.11f    // 5-sigma fp16 noise (0.09) + 6-bit idx-pack noise (0.016)
#define PRUNE_MARGIN 0.28f  // 2*theta + 6*sigma error bound + pack noise
#define SBIAS 4096.0f       // positivity bias so packed-float order == value order

// ---------------- workspace layout (BYTE offsets) ----------------
#define B_AHAT  0ull          // 32768*256 f16 = 16777216 B  Xh
#define B_BHAT  16777216ull   // 4096*256 f16  = 2097152 B   Ch
#define B_PART  18874368ull   // 32768*64 float2 = 16777216 B per-64col-chunk (b1|idx, b2)
#define B_CE    52428800ull   // 4096 f32
#define B_CNTI  52445184ull   // 4096 int: integer counts
#define B_CSP   52461568ull   // 4096 f32: cs_pre
#define B_NPTR  52494336ull   // f32 n (plain store by scan_cs; no memset needed)
#define B_DW    53018688ull   // 4096*256 f32 = 4194304 B segment sums (atomic)
// total ~57.2 MB

// ---------------- output layout (float offsets) ----------------
#define OFF_Q  0ull                 // quantized  [32768,256]
#define OFF_E  8388608ull           // encodings  [32768,4096]
#define OFF_CB 142606336ull         // new_codebook [4096,256]
#define OFF_W  143654912ull         // new_ema_w    [4096,256]
#define OFF_CS 144703488ull         // cs [4096]

typedef __attribute__((ext_vector_type(8))) _Float16 f16x8;
typedef __attribute__((ext_vector_type(4))) _Float16 f16x4;
typedef __attribute__((ext_vector_type(4))) float f32x4;

// ---- fused prep: X cast (blocks 0..4095), cb cast + norms (4096..5119),
// countsI zero (5120..5135), dw zero (5136..6159).
__global__ __launch_bounds__(256) void prep_kernel(const float* __restrict__ xg,
                                                   const float* __restrict__ cbg,
                                                   _Float16* __restrict__ Ahat,
                                                   _Float16* __restrict__ Bhat,
                                                   float* __restrict__ ce,
                                                   int* __restrict__ countsI,
                                                   float4* __restrict__ dwv) {
    int b = blockIdx.x;
    int tid = threadIdx.x;
    if (b < 4096) {
        size_t gid = (size_t)b * 256 + tid;
        const float* sp = xg + gid * 8;
        f16x8 v;
        #pragma unroll
        for (int t = 0; t < 8; ++t) v[t] = (_Float16)sp[t];
        *(f16x8*)(Ahat + gid * 8) = v;
    } else if (b < 5120) {
        int k = (b - 4096) * 4 + (tid >> 6);
        int lane = tid & 63;
        float4 v = *(const float4*)(cbg + (size_t)k * DDIM + lane * 4);
        f16x4 h;
        h[0] = (_Float16)v.x; h[1] = (_Float16)v.y;
        h[2] = (_Float16)v.z; h[3] = (_Float16)v.w;
        *(f16x4*)(Bhat + (size_t)k * DDIM + lane * 4) = h;
        float s = v.x * v.x + v.y * v.y + v.z * v.z + v.w * v.w;
        #pragma unroll
        for (int o = 32; o > 0; o >>= 1) s += __shfl_down(s, o);
        if (lane == 0) ce[k] = s;
    } else if (b < 5136) {
        countsI[(b - 5120) * 256 + tid] = 0;
    } else {
        float4 z = {0.f, 0.f, 0.f, 0.f};
        dwv[(size_t)(b - 5136) * 256 + tid] = z;
    }
}

// ---- fp16 MFMA GEMM (M=32768, N=4096, K=256) with fused per-row argmin.
// 128x128 tile, BK=64, global_load_lds width-16, XOR-swizzled staging,
// XCD-aware bijective remap, packed-idx float2 part epilogue.
// Each block also zeroes a 64 KB slice of enc with nontemporal stores
// issued at the VERY END (no barrier follows -> fire-and-forget; retires
// in the shadow of other blocks' MFMA). post (next dispatch) writes only
// the one-hot 1.0f -- kernel-boundary visibility, NO per-block fence
// (the R4 per-block __threadfence() L2-flush disaster, 2% MfmaUtil).
__global__ __launch_bounds__(256) void gemm_argmin_kernel(
        const _Float16* __restrict__ Ahat,
        const _Float16* __restrict__ Bhat,
        const float* __restrict__ ceg,
        float2* __restrict__ part,
        float* __restrict__ enc) {
    __shared__ _Float16 As[128 * 64];   // 16 KB
    __shared__ _Float16 Bs[128 * 64];   // 16 KB
    const int tid  = threadIdx.x;
    const int lane = tid & 63;
    const int wave = tid >> 6;
    const int wm = wave >> 1, wn = wave & 1;  // 2x2 wave grid, 64x64 per wave

    int lin = blockIdx.y * 32 + blockIdx.x;
    lin = (lin & 7) * 1024 + (lin >> 3);      // bijective: 8192 = 8 * 1024
    const int nb = lin & 31, mb = lin >> 5;   // nb fast: A-tile sharers adjacent

    const int col = lane & 15, q = lane >> 4;
    const int cswz = q ^ (col & 7);           // reader chunk swizzle base

    const int srow = tid >> 3;
    const int sswz = (tid & 7) ^ (srow & 7);
    const _Float16* ag = Ahat + (size_t)(mb * 128 + srow) * KSPLIT + sswz * 8;
    const _Float16* bg = Bhat + (size_t)(nb * 128 + srow) * KSPLIT + sswz * 8;

    f32x4 zero = {0.f, 0.f, 0.f, 0.f};
    f32x4 acc[4][4];
    #pragma unroll
    for (int i = 0; i < 4; ++i)
        #pragma unroll
        for (int j = 0; j < 4; ++j) acc[i][j] = zero;

    for (int kt = 0; kt < KSPLIT / 64; ++kt) {
        __syncthreads();
        #pragma unroll
        for (int n = 0; n < 4; ++n) {
            __builtin_amdgcn_global_load_lds(
                (const __attribute__((address_space(1))) void*)(ag + (size_t)n * 32 * KSPLIT + kt * 64),
                (__attribute__((address_space(3))) void*)(As + n * 2048 + tid * 8), 16, 0, 0);
            __builtin_amdgcn_global_load_lds(
                (const __attribute__((address_space(1))) void*)(bg + (size_t)n * 32 * KSPLIT + kt * 64),
                (__attribute__((address_space(3))) void*)(Bs + n * 2048 + tid * 8), 16, 0, 0);
        }
        __syncthreads();

        const f16x8* Av = (const f16x8*)As;
        const f16x8* Bv = (const f16x8*)Bs;
        #pragma unroll
        for (int ks = 0; ks < 2; ++ks) {
            f16x8 a[4], b[4];
            #pragma unroll
            for (int i = 0; i < 4; ++i)
                a[i] = Av[(wm * 64 + i * 16 + col) * 8 + (cswz ^ (ks * 4))];
            #pragma unroll
            for (int j = 0; j < 4; ++j)
                b[j] = Bv[(wn * 64 + j * 16 + col) * 8 + (cswz ^ (ks * 4))];
            #pragma unroll
            for (int i = 0; i < 4; ++i)
                #pragma unroll
                for (int j = 0; j < 4; ++j)
                    acc[i][j] = __builtin_amdgcn_mfma_f32_16x16x32_f16(a[i], b[j], acc[i][j], 0, 0, 0);
        }
    }

    // epilogue: s = ||c||^2 - 2*dot + SBIAS (positive), pack local idx into
    // low 6 mantissa bits -> min on packed floats == min-with-tiebreak.
    float ce_j[4];
    #pragma unroll
    for (int j = 0; j < 4; ++j) ce_j[j] = ceg[nb * 128 + wn * 64 + j * 16 + col];

    #pragma unroll
    for (int i = 0; i < 4; ++i) {
        #pragma unroll
        for (int r = 0; r < 4; ++r) {
            float p1 = 3.4e38f, p2 = 3.4e38f;
            #pragma unroll
            for (int j = 0; j < 4; ++j) {
                float s = ce_j[j] - 2.0f * acc[i][j][r] + SBIAS;
                int loc = j * 16 + col;                  // 6-bit chunk-local idx
                float sp = __int_as_float((__float_as_int(s) & ~63) | loc);
                if (sp < p1) { p2 = p1; p1 = sp; }
                else if (sp < p2) { p2 = sp; }
            }
            #pragma unroll
            for (int m = 1; m < 16; m <<= 1) {
                float o1 = __shfl_xor(p1, m, 16);
                float o2 = __shfl_xor(p2, m, 16);
                float lo = fminf(p1, o1);
                float hi = fmaxf(p1, o1);
                p2 = fminf(hi, fminf(p2, o2));
                p1 = lo;
            }
            if (col == i * 4 + r) {   // unique writer lane per (q,i,r)
                int mrow = mb * 128 + wm * 64 + i * 16 + q * 4 + r;
                float2 p;
                p.x = p1; p.y = p2;
                part[(size_t)mrow * 64 + nb * 2 + wn] = p;
            }
        }
    }

    // ---- enc zero slice: 64 KB per block, nontemporal, fire-and-forget.
    // 537 MB total spread over 8192 blocks; lin is a permutation -> exact
    // cover. (ext_vector f32x4 -- builtin rejects HIP struct float4.)
    {
        f32x4* ez = (f32x4*)(enc + (size_t)lin * 16384) + tid;
        f32x4 z4 = {0.f, 0.f, 0.f, 0.f};
        #pragma unroll
        for (int v = 0; v < 16; ++v)
            __builtin_nontemporal_store(z4, ez + v * 256);
    }
}

// ---- fused post-process: one wave per token.
//   (1) 64-chunk 2-value butterfly merge (packed floats)
//   (2) near-tie -> in-wave chunk-pruned fp64 refine (exact, incl. ties)
//   (3) count atomic + one-hot 1.0f store + quant row gather-copy
//   (4) NEW: dw segment-sum via direct atomicAdd of the x row (replaces
//       the whole CSR pipeline: tokIdx/tlist/offs/filllist/segdw gone).
//       8.4M f32 atomics over 1M distinct L2-resident addresses, avg 8
//       colliders each -- same fp-order-nondeterminism class as segdw had.
__global__ __launch_bounds__(256) void post_kernel(const float* __restrict__ xg,
                                                   const float* __restrict__ cb,
                                                   const float2* __restrict__ part,
                                                   int* __restrict__ countsI,
                                                   float* __restrict__ quant,
                                                   float* __restrict__ enc,
                                                   float* __restrict__ dw) {
    int row = blockIdx.x * 4 + (threadIdx.x >> 6);
    int lane = threadIdx.x & 63;
    float2 p = part[(size_t)row * 64 + lane];
    float own = p.x;                       // this lane's chunk-best (packed)
    float b1 = p.x, b2 = p.y;
    #pragma unroll
    for (int m = 1; m < 64; m <<= 1) {
        float o1 = __shfl_xor(b1, m);
        float o2 = __shfl_xor(b2, m);
        float lo = fminf(b1, o1);
        float hi = fmaxf(b1, o1);
        b2 = fminf(hi, fminf(b2, o2));
        b1 = lo;
    }
    // every lane holds identical (b1,b2). Winner chunk = lowest lane whose
    // own packed best equals the global best.
    int kfin;
    {
        unsigned long long wmask = __ballot(own == b1);
        int wl = __ffsll(wmask) - 1;
        kfin = wl * 64 + (__float_as_int(b1) & 63);
    }
    if (b2 - b1 < FLAG_THETA) {
        // chunk-pruned fp64 refine, wave-uniform branch (exact tie-breaks).
        unsigned long long mask = __ballot(own <= b1 + PRUNE_MARGIN);
        double best = 1e300;
        int bi = 0x7fffffff;
        const float* xr = xg + (size_t)row * DDIM;
        while (mask) {
            int c = __ffsll(mask) - 1;
            mask &= mask - 1;
            int k = c * 64 + lane;
            const float* e = cb + (size_t)k * DDIM;
            double s = 0.0;
            for (int d4 = 0; d4 < DDIM / 4; ++d4) {
                float4 e4 = *(const float4*)(e + d4 * 4);
                float4 x4 = *(const float4*)(xr + d4 * 4);
                double e0 = (double)e4.x, e1 = (double)e4.y;
                double e2 = (double)e4.z, e3 = (double)e4.w;
                s += e0 * (e0 - 2.0 * (double)x4.x) + e1 * (e1 - 2.0 * (double)x4.y)
                   + e2 * (e2 - 2.0 * (double)x4.z) + e3 * (e3 - 2.0 * (double)x4.w);
            }
            if (s < best || (s == best && k < bi)) { best = s; bi = k; }
        }
        #pragma unroll
        for (int m = 1; m < 64; m <<= 1) {
            double ob = __shfl_xor(best, m);
            int   oi  = __shfl_xor(bi, m);
            if (ob < best || (ob == best && oi < bi)) { best = ob; bi = oi; }
        }
        kfin = bi;                          // uniform across lanes
    }
    if (lane == 0) {
        atomicAdd(countsI + kfin, 1);
        enc[(size_t)row * KEMB + kfin] = 1.0f;   // zeros pre-written by GEMM
    }
    float4 e = *(const float4*)(cb + (size_t)kfin * DDIM + lane * 4);
    *(float4*)(quant + (size_t)row * DDIM + lane * 4) = e;
    // dw[kfin] += x[row]  (direct segment-sum; x is L3-warm from prep)
    {
        float4 x4 = *(const float4*)(xg + (size_t)row * DDIM + lane * 4);
        float* dp = dw + (size_t)kfin * DDIM + lane * 4;
        atomicAdd(dp + 0, x4.x);
        atomicAdd(dp + 1, x4.y);
        atomicAdd(dp + 2, x4.z);
        atomicAdd(dp + 3, x4.w);
    }
}

// ---- cs pass: single block. cs_pre = ema_cs*decay + (1-decay)*counts,
// n = sum(cs_pre) (plain store; no offsets needed anymore).
__global__ __launch_bounds__(256) void scan_cs_kernel(const int* __restrict__ countsI,
                                                      const float* __restrict__ ema_cs,
                                                      float* __restrict__ cs_pre,
                                                      float* __restrict__ nptr) {
    __shared__ float npart[256];
    int tid = threadIdx.x;
    float ns = 0.0f;
    #pragma unroll
    for (int i = 0; i < 16; ++i) {
        int c = countsI[tid * 16 + i];
        float csp = ema_cs[tid * 16 + i] * DECAYF + (1.0f - DECAYF) * (float)c;
        cs_pre[tid * 16 + i] = csp;
        ns += csp;
    }
    npart[tid] = ns;
    __syncthreads();
    if (tid == 0) {
        float nn = 0.0f;
        for (int i = 0; i < 256; ++i) nn += npart[i];
        nptr[0] = nn;
    }
}

// ---- epilogue: new_ema_w, laplace-smoothed cs, new_codebook ----
__global__ __launch_bounds__(256) void epi_kernel(const float* __restrict__ ema_w,
                                                  const float* __restrict__ dw,
                                                  const float* __restrict__ cs_pre,
                                                  const float* __restrict__ nptr,
                                                  float* __restrict__ new_cb,
                                                  float* __restrict__ new_w,
                                                  float* __restrict__ cs_out) {
    int gid = blockIdx.x * 256 + threadIdx.x;   // 0 .. 1048575
    int k = gid >> 8, d = gid & 255;
    float n = *nptr;
    float csp = cs_pre[k];
    float cs = (csp + EPSF) / (n + (float)KEMB * EPSF) * n;
    float w = ema_w[gid] * DECAYF + (1.0f - DECAYF) * dw[gid];
    new_w[gid] = w;
    new_cb[gid] = w / cs;
    if (d == 0) cs_out[k] = cs;
}

extern "C" void kernel_launch(void* const* d_in, const int* in_sizes, int n_in,
                              void* d_out, int out_size, void* d_ws, size_t ws_size,
                              hipStream_t stream) {
    const float* xg     = (const float*)d_in[0];   // [32768,256]
    const float* cbg    = (const float*)d_in[1];   // [4096,256]
    const float* ema_w  = (const float*)d_in[2];   // [4096,256]
    const float* ema_cs = (const float*)d_in[3];   // [4096]

    float* out = (float*)d_out;
    unsigned char* wsb = (unsigned char*)d_ws;

    float* quant  = out + OFF_Q;
    float* enc    = out + OFF_E;
    float* new_cb = out + OFF_CB;
    float* new_w  = out + OFF_W;
    float* cs_out = out + OFF_CS;

    _Float16* Ahat = (_Float16*)(wsb + B_AHAT);
    _Float16* Bhat = (_Float16*)(wsb + B_BHAT);
    float2* part   = (float2*)(wsb + B_PART);
    float* ce      = (float*)(wsb + B_CE);
    int*   countsI = (int*)(wsb + B_CNTI);
    float* cs_pre  = (float*)(wsb + B_CSP);
    float* nptr    = (float*)(wsb + B_NPTR);
    float* dw      = (float*)(wsb + B_DW);

    // 5 dispatches. No memsets: enc zeros streamed from the GEMM blocks
    // (nontemporal, shadowed); countsI/dw zeroed in prep; nptr plain-stored.
    // CSR pipeline (tokIdx/tlist/offs/filllist/segdw) replaced by direct
    // dw atomics in post.
    prep_kernel<<<6160, 256, 0, stream>>>(xg, cbg, Ahat, Bhat, ce, countsI, (float4*)dw);
    gemm_argmin_kernel<<<dim3(KEMB / 128, NTOK / 128), 256, 0, stream>>>(Ahat, Bhat, ce, part, enc);
    post_kernel<<<NTOK / 4, 256, 0, stream>>>(xg, cbg, part, countsI, quant, enc, dw);
    scan_cs_kernel<<<1, 256, 0, stream>>>(countsI, ema_cs, cs_pre, nptr);
    epi_kernel<<<(KEMB * DDIM) / 256, 256, 0, stream>>>(ema_w, dw, cs_pre, nptr,
                                                        new_cb, new_w, cs_out);
}

// Round 8
// 722.275 us; speedup vs baseline: 1.1817x; 1.1817x over previous
//
#include <hip/hip_runtime.h>
#include <hip/hip_bf16.h>

#define NTOK 32768
#define KEMB 4096
#define DDIM 256
#define DECAYF 0.99f
#define EPSF 1e-5f
#define KSPLIT 256          // hi-only fp16: Xh . Ch, error handled by flag+refine
#define FLAG_THETA 0.11f    // 5-sigma fp16 noise (0.09) + 6-bit idx-pack noise (0.016)
#define PRUNE_MARGIN 0.28f  // 2*theta + 6*sigma error bound + pack noise
#define SBIAS 4096.0f       // positivity bias so packed-float order == value order

// ---------------- workspace layout (BYTE offsets) ----------------
#define B_AHAT  0ull          // 32768*256 f16 = 16777216 B  Xh
#define B_BHAT  16777216ull   // 4096*256 f16  = 2097152 B   Ch
#define B_PART  18874368ull   // 32768*64 float2 = 16777216 B per-64col-chunk (b1|idx, b2)
#define B_CE    52428800ull   // 4096 f32
#define B_CNTI  52445184ull   // 4096 int: integer counts
#define B_CSP   52461568ull   // 4096 f32: cs_pre
#define B_OFFS  52477952ull   // 4096 int: CSR offsets (atomically consumed by filllist)
#define B_NPTR  52494336ull   // f32 n (plain store by scan_cs; no memset needed)
#define B_TIDX  52494400ull   // 32768 int: per-token argmin
#define B_TLIST 52887616ull   // 32768 int: CSR token list
#define B_DW    53018688ull   // 4096*256 f32 = 4194304 B segment sums
// total ~57.2 MB

// ---------------- output layout (float offsets) ----------------
#define OFF_Q  0ull                 // quantized  [32768,256]
#define OFF_E  8388608ull           // encodings  [32768,4096]
#define OFF_CB 142606336ull         // new_codebook [4096,256]
#define OFF_W  143654912ull         // new_ema_w    [4096,256]
#define OFF_CS 144703488ull         // cs [4096]

typedef __attribute__((ext_vector_type(8))) _Float16 f16x8;
typedef __attribute__((ext_vector_type(4))) _Float16 f16x4;
typedef __attribute__((ext_vector_type(4))) float f32x4;

// ---- fused prep: X cast (blocks 0..4095), cb cast + norms (4096..5119),
// countsI zero (5120..5135), dw zero (5136..6159).
__global__ __launch_bounds__(256) void prep_kernel(const float* __restrict__ xg,
                                                   const float* __restrict__ cbg,
                                                   _Float16* __restrict__ Ahat,
                                                   _Float16* __restrict__ Bhat,
                                                   float* __restrict__ ce,
                                                   int* __restrict__ countsI,
                                                   float4* __restrict__ dwv) {
    int b = blockIdx.x;
    int tid = threadIdx.x;
    if (b < 4096) {
        size_t gid = (size_t)b * 256 + tid;
        const float* sp = xg + gid * 8;
        f16x8 v;
        #pragma unroll
        for (int t = 0; t < 8; ++t) v[t] = (_Float16)sp[t];
        *(f16x8*)(Ahat + gid * 8) = v;
    } else if (b < 5120) {
        int k = (b - 4096) * 4 + (tid >> 6);
        int lane = tid & 63;
        float4 v = *(const float4*)(cbg + (size_t)k * DDIM + lane * 4);
        f16x4 h;
        h[0] = (_Float16)v.x; h[1] = (_Float16)v.y;
        h[2] = (_Float16)v.z; h[3] = (_Float16)v.w;
        *(f16x4*)(Bhat + (size_t)k * DDIM + lane * 4) = h;
        float s = v.x * v.x + v.y * v.y + v.z * v.z + v.w * v.w;
        #pragma unroll
        for (int o = 32; o > 0; o >>= 1) s += __shfl_down(s, o);
        if (lane == 0) ce[k] = s;
    } else if (b < 5136) {
        countsI[(b - 5120) * 256 + tid] = 0;
    } else {
        float4 z = {0.f, 0.f, 0.f, 0.f};
        dwv[(size_t)(b - 5136) * 256 + tid] = z;
    }
}

// ---- fp16 MFMA GEMM (M=32768, N=4096, K=256) with fused per-row argmin.
// 128x128 tile, BK=64, global_load_lds width-16, XOR-swizzled staging,
// XCD-aware bijective remap, packed-idx float2 part epilogue.
// Each block also zeroes a 64 KB slice of enc with nontemporal stores
// issued at the VERY END (no barrier follows -> fire-and-forget; retires
// in the shadow of other blocks' MFMA). post (next dispatch) writes only
// the one-hot 1.0f -- kernel-boundary visibility, NO per-block fence
// (the R4 per-block __threadfence() L2-flush disaster, 2% MfmaUtil).
__global__ __launch_bounds__(256) void gemm_argmin_kernel(
        const _Float16* __restrict__ Ahat,
        const _Float16* __restrict__ Bhat,
        const float* __restrict__ ceg,
        float2* __restrict__ part,
        float* __restrict__ enc) {
    __shared__ _Float16 As[128 * 64];   // 16 KB
    __shared__ _Float16 Bs[128 * 64];   // 16 KB
    const int tid  = threadIdx.x;
    const int lane = tid & 63;
    const int wave = tid >> 6;
    const int wm = wave >> 1, wn = wave & 1;  // 2x2 wave grid, 64x64 per wave

    int lin = blockIdx.y * 32 + blockIdx.x;
    lin = (lin & 7) * 1024 + (lin >> 3);      // bijective: 8192 = 8 * 1024
    const int nb = lin & 31, mb = lin >> 5;   // nb fast: A-tile sharers adjacent

    const int col = lane & 15, q = lane >> 4;
    const int cswz = q ^ (col & 7);           // reader chunk swizzle base

    const int srow = tid >> 3;
    const int sswz = (tid & 7) ^ (srow & 7);
    const _Float16* ag = Ahat + (size_t)(mb * 128 + srow) * KSPLIT + sswz * 8;
    const _Float16* bg = Bhat + (size_t)(nb * 128 + srow) * KSPLIT + sswz * 8;

    f32x4 zero = {0.f, 0.f, 0.f, 0.f};
    f32x4 acc[4][4];
    #pragma unroll
    for (int i = 0; i < 4; ++i)
        #pragma unroll
        for (int j = 0; j < 4; ++j) acc[i][j] = zero;

    for (int kt = 0; kt < KSPLIT / 64; ++kt) {
        __syncthreads();
        #pragma unroll
        for (int n = 0; n < 4; ++n) {
            __builtin_amdgcn_global_load_lds(
                (const __attribute__((address_space(1))) void*)(ag + (size_t)n * 32 * KSPLIT + kt * 64),
                (__attribute__((address_space(3))) void*)(As + n * 2048 + tid * 8), 16, 0, 0);
            __builtin_amdgcn_global_load_lds(
                (const __attribute__((address_space(1))) void*)(bg + (size_t)n * 32 * KSPLIT + kt * 64),
                (__attribute__((address_space(3))) void*)(Bs + n * 2048 + tid * 8), 16, 0, 0);
        }
        __syncthreads();

        const f16x8* Av = (const f16x8*)As;
        const f16x8* Bv = (const f16x8*)Bs;
        #pragma unroll
        for (int ks = 0; ks < 2; ++ks) {
            f16x8 a[4], b[4];
            #pragma unroll
            for (int i = 0; i < 4; ++i)
                a[i] = Av[(wm * 64 + i * 16 + col) * 8 + (cswz ^ (ks * 4))];
            #pragma unroll
            for (int j = 0; j < 4; ++j)
                b[j] = Bv[(wn * 64 + j * 16 + col) * 8 + (cswz ^ (ks * 4))];
            #pragma unroll
            for (int i = 0; i < 4; ++i)
                #pragma unroll
                for (int j = 0; j < 4; ++j)
                    acc[i][j] = __builtin_amdgcn_mfma_f32_16x16x32_f16(a[i], b[j], acc[i][j], 0, 0, 0);
        }
    }

    // epilogue: s = ||c||^2 - 2*dot + SBIAS (positive), pack local idx into
    // low 6 mantissa bits -> min on packed floats == min-with-tiebreak.
    float ce_j[4];
    #pragma unroll
    for (int j = 0; j < 4; ++j) ce_j[j] = ceg[nb * 128 + wn * 64 + j * 16 + col];

    #pragma unroll
    for (int i = 0; i < 4; ++i) {
        #pragma unroll
        for (int r = 0; r < 4; ++r) {
            float p1 = 3.4e38f, p2 = 3.4e38f;
            #pragma unroll
            for (int j = 0; j < 4; ++j) {
                float s = ce_j[j] - 2.0f * acc[i][j][r] + SBIAS;
                int loc = j * 16 + col;                  // 6-bit chunk-local idx
                float sp = __int_as_float((__float_as_int(s) & ~63) | loc);
                if (sp < p1) { p2 = p1; p1 = sp; }
                else if (sp < p2) { p2 = sp; }
            }
            #pragma unroll
            for (int m = 1; m < 16; m <<= 1) {
                float o1 = __shfl_xor(p1, m, 16);
                float o2 = __shfl_xor(p2, m, 16);
                float lo = fminf(p1, o1);
                float hi = fmaxf(p1, o1);
                p2 = fminf(hi, fminf(p2, o2));
                p1 = lo;
            }
            if (col == i * 4 + r) {   // unique writer lane per (q,i,r)
                int mrow = mb * 128 + wm * 64 + i * 16 + q * 4 + r;
                float2 p;
                p.x = p1; p.y = p2;
                part[(size_t)mrow * 64 + nb * 2 + wn] = p;
            }
        }
    }

    // ---- enc zero slice: 64 KB per block, nontemporal, fire-and-forget.
    // 537 MB total spread over 8192 blocks; lin is a permutation -> exact
    // cover. (ext_vector f32x4 -- builtin rejects HIP struct float4.)
    {
        f32x4* ez = (f32x4*)(enc + (size_t)lin * 16384) + tid;
        f32x4 z4 = {0.f, 0.f, 0.f, 0.f};
        #pragma unroll
        for (int v = 0; v < 16; ++v)
            __builtin_nontemporal_store(z4, ez + v * 256);
    }
}

// ---- slim post-process: one wave per token.
//   (1) 64-chunk 2-value butterfly merge (packed floats)
//   (2) near-tie -> in-wave chunk-pruned fp64 refine (exact, incl. ties)
//   (3) count atomic + one-hot 1.0f store (zeros pre-written by GEMM) +
//       quant row gather-copy (nontemporal: streamed once, never re-read)
// dw stays on the CSR+segdw path: R7 proved direct dw atomics collapse
// under heavy-tailed cluster occupancy (+118 us).
__global__ __launch_bounds__(256) void post_kernel(const float* __restrict__ xg,
                                                   const float* __restrict__ cb,
                                                   const float2* __restrict__ part,
                                                   int* __restrict__ tokIdx,
                                                   int* __restrict__ countsI,
                                                   float* __restrict__ quant,
                                                   float* __restrict__ enc) {
    int row = blockIdx.x * 4 + (threadIdx.x >> 6);
    int lane = threadIdx.x & 63;
    float2 p = part[(size_t)row * 64 + lane];
    float own = p.x;                       // this lane's chunk-best (packed)
    float b1 = p.x, b2 = p.y;
    #pragma unroll
    for (int m = 1; m < 64; m <<= 1) {
        float o1 = __shfl_xor(b1, m);
        float o2 = __shfl_xor(b2, m);
        float lo = fminf(b1, o1);
        float hi = fmaxf(b1, o1);
        b2 = fminf(hi, fminf(b2, o2));
        b1 = lo;
    }
    // every lane holds identical (b1,b2). Winner chunk = lowest lane whose
    // own packed best equals the global best.
    int kfin;
    {
        unsigned long long wmask = __ballot(own == b1);
        int wl = __ffsll(wmask) - 1;
        kfin = wl * 64 + (__float_as_int(b1) & 63);
    }
    if (b2 - b1 < FLAG_THETA) {
        // chunk-pruned fp64 refine, wave-uniform branch (exact tie-breaks).
        unsigned long long mask = __ballot(own <= b1 + PRUNE_MARGIN);
        double best = 1e300;
        int bi = 0x7fffffff;
        const float* xr = xg + (size_t)row * DDIM;
        while (mask) {
            int c = __ffsll(mask) - 1;
            mask &= mask - 1;
            int k = c * 64 + lane;
            const float* e = cb + (size_t)k * DDIM;
            double s = 0.0;
            for (int d4 = 0; d4 < DDIM / 4; ++d4) {
                float4 e4 = *(const float4*)(e + d4 * 4);
                float4 x4 = *(const float4*)(xr + d4 * 4);
                double e0 = (double)e4.x, e1 = (double)e4.y;
                double e2 = (double)e4.z, e3 = (double)e4.w;
                s += e0 * (e0 - 2.0 * (double)x4.x) + e1 * (e1 - 2.0 * (double)x4.y)
                   + e2 * (e2 - 2.0 * (double)x4.z) + e3 * (e3 - 2.0 * (double)x4.w);
            }
            if (s < best || (s == best && k < bi)) { best = s; bi = k; }
        }
        #pragma unroll
        for (int m = 1; m < 64; m <<= 1) {
            double ob = __shfl_xor(best, m);
            int   oi  = __shfl_xor(bi, m);
            if (ob < best || (ob == best && oi < bi)) { best = ob; bi = oi; }
        }
        kfin = bi;                          // uniform across lanes
    }
    if (lane == 0) {
        tokIdx[row] = kfin;
        atomicAdd(countsI + kfin, 1);
        enc[(size_t)row * KEMB + kfin] = 1.0f;   // zeros pre-written by GEMM
    }
    f32x4 e = *(const f32x4*)(cb + (size_t)kfin * DDIM + lane * 4);
    __builtin_nontemporal_store(e, (f32x4*)(quant + (size_t)row * DDIM + lane * 4));
}

// ---- CSR pass 2 + cs: single block. Exclusive scan of countsI -> offs,
// cs_pre = ema_cs*decay + (1-decay)*counts, n = sum(cs_pre) (plain store).
__global__ __launch_bounds__(256) void scan_cs_kernel(const int* __restrict__ countsI,
                                                      const float* __restrict__ ema_cs,
                                                      int* __restrict__ offs,
                                                      float* __restrict__ cs_pre,
                                                      float* __restrict__ nptr) {
    __shared__ int part[256];
    __shared__ float npart[256];
    __shared__ int pref[257];
    int tid = threadIdx.x;
    int local[16];
    int s = 0;
    float ns = 0.0f;
    #pragma unroll
    for (int i = 0; i < 16; ++i) {
        int c = countsI[tid * 16 + i];
        local[i] = c;
        s += c;
        float csp = ema_cs[tid * 16 + i] * DECAYF + (1.0f - DECAYF) * (float)c;
        cs_pre[tid * 16 + i] = csp;
        ns += csp;
    }
    part[tid] = s;
    npart[tid] = ns;
    __syncthreads();
    if (tid == 0) {
        pref[0] = 0;
        float nn = 0.0f;
        for (int i = 0; i < 256; ++i) {
            pref[i + 1] = pref[i] + part[i];
            nn += npart[i];
        }
        nptr[0] = nn;
    }
    __syncthreads();
    int run = pref[tid];
    #pragma unroll
    for (int i = 0; i < 16; ++i) { offs[tid * 16 + i] = run; run += local[i]; }
}

// ---- CSR pass 3: fill token list. offs doubles as the slot cursor. ----
__global__ __launch_bounds__(256) void filllist_kernel(const int* __restrict__ tokIdx,
                                                       int* __restrict__ offs,
                                                       int* __restrict__ tlist) {
    int t = blockIdx.x * 256 + threadIdx.x;
    int k = tokIdx[t];
    int slot = atomicAdd(offs + k, 1);
    tlist[slot] = t;
}

// ---- balanced segmented dw reduction over the CSR list ----
#define SEG_CHUNK 32
__global__ __launch_bounds__(256) void segdw_kernel(const float* __restrict__ xg,
                                                    const int* __restrict__ tlist,
                                                    const int* __restrict__ tokIdx,
                                                    float* __restrict__ dw) {
    int tid = threadIdx.x;
    int s0 = blockIdx.x * SEG_CHUNK;
    float acc = 0.0f;
    int curk = -1;
    for (int s = s0; s < s0 + SEG_CHUNK; ++s) {
        int t = tlist[s];
        int k = tokIdx[t];
        if (k != curk) {
            if (curk >= 0) atomicAdd(dw + (size_t)curk * DDIM + tid, acc);
            acc = 0.0f;
            curk = k;
        }
        acc += xg[(size_t)t * DDIM + tid];
    }
    if (curk >= 0) atomicAdd(dw + (size_t)curk * DDIM + tid, acc);
}

// ---- epilogue: new_ema_w, laplace-smoothed cs, new_codebook ----
__global__ __launch_bounds__(256) void epi_kernel(const float* __restrict__ ema_w,
                                                  const float* __restrict__ dw,
                                                  const float* __restrict__ cs_pre,
                                                  const float* __restrict__ nptr,
                                                  float* __restrict__ new_cb,
                                                  float* __restrict__ new_w,
                                                  float* __restrict__ cs_out) {
    int gid = blockIdx.x * 256 + threadIdx.x;   // 0 .. 1048575
    int k = gid >> 8, d = gid & 255;
    float n = *nptr;
    float csp = cs_pre[k];
    float cs = (csp + EPSF) / (n + (float)KEMB * EPSF) * n;
    float w = ema_w[gid] * DECAYF + (1.0f - DECAYF) * dw[gid];
    new_w[gid] = w;
    new_cb[gid] = w / cs;
    if (d == 0) cs_out[k] = cs;
}

extern "C" void kernel_launch(void* const* d_in, const int* in_sizes, int n_in,
                              void* d_out, int out_size, void* d_ws, size_t ws_size,
                              hipStream_t stream) {
    const float* xg     = (const float*)d_in[0];   // [32768,256]
    const float* cbg    = (const float*)d_in[1];   // [4096,256]
    const float* ema_w  = (const float*)d_in[2];   // [4096,256]
    const float* ema_cs = (const float*)d_in[3];   // [4096]

    float* out = (float*)d_out;
    unsigned char* wsb = (unsigned char*)d_ws;

    float* quant  = out + OFF_Q;
    float* enc    = out + OFF_E;
    float* new_cb = out + OFF_CB;
    float* new_w  = out + OFF_W;
    float* cs_out = out + OFF_CS;

    _Float16* Ahat = (_Float16*)(wsb + B_AHAT);
    _Float16* Bhat = (_Float16*)(wsb + B_BHAT);
    float2* part   = (float2*)(wsb + B_PART);
    float* ce      = (float*)(wsb + B_CE);
    int*   countsI = (int*)(wsb + B_CNTI);
    float* cs_pre  = (float*)(wsb + B_CSP);
    int*   offs    = (int*)(wsb + B_OFFS);
    float* nptr    = (float*)(wsb + B_NPTR);
    int*   tokIdx  = (int*)(wsb + B_TIDX);
    int*   tlist   = (int*)(wsb + B_TLIST);
    float* dw      = (float*)(wsb + B_DW);

    // 7 dispatches (R6 structure, proven 735 us). No memsets: enc zeros
    // streamed from the GEMM blocks (nontemporal, shadowed); countsI/dw
    // zeroed in prep; nptr plain-stored by scan_cs. dw via sorted CSR +
    // segdw (R7 proved direct atomics lose to contention skew).
    prep_kernel<<<6160, 256, 0, stream>>>(xg, cbg, Ahat, Bhat, ce, countsI, (float4*)dw);
    gemm_argmin_kernel<<<dim3(KEMB / 128, NTOK / 128), 256, 0, stream>>>(Ahat, Bhat, ce, part, enc);
    post_kernel<<<NTOK / 4, 256, 0, stream>>>(xg, cbg, part, tokIdx, countsI, quant, enc);
    scan_cs_kernel<<<1, 256, 0, stream>>>(countsI, ema_cs, offs, cs_pre, nptr);
    filllist_kernel<<<NTOK / 256, 256, 0, stream>>>(tokIdx, offs, tlist);
    segdw_kernel<<<NTOK / SEG_CHUNK, 256, 0, stream>>>(xg, tlist, tokIdx, dw);
    epi_kernel<<<(KEMB * DDIM) / 256, 256, 0, stream>>>(ema_w, dw, cs_pre, nptr,
                                                        new_cb, new_w, cs_out);
}